// Round 6
// baseline (16873.253 us; speedup 1.0000x reference)
//
#include <hip/hip_runtime.h>

typedef short bf8 __attribute__((ext_vector_type(8)));   // 8 bf16 raw bits (4 VGPRs)
typedef float f4  __attribute__((ext_vector_type(4)));
typedef int   i4  __attribute__((ext_vector_type(4)));

#define DEV static __device__ __forceinline__

DEV float bf2f(unsigned short u){ unsigned int x = ((unsigned int)u) << 16; float f; __builtin_memcpy(&f, &x, 4); return f; }
DEV unsigned short f2bf(float f){ unsigned int x; __builtin_memcpy(&x, &f, 4); unsigned int r = (x + 0x7fffu + ((x >> 16) & 1u)) >> 16; return (unsigned short)r; }
DEV float sigm(float z){ return 1.f / (1.f + __expf(-z)); }
DEV float tanh_fast(float z){ float e = __expf(2.f * z); return 1.f - 2.f / (e + 1.f); }
DEV bf8 ld16(const unsigned short* p){ return __builtin_bit_cast(bf8, *(const i4*)p); }

// ---------------------------------------------------------------- cvt f32->bf16
__global__ void k_cvt(const float* __restrict__ s, unsigned short* __restrict__ d, int n){
    int i = blockIdx.x * 256 + threadIdx.x;
    if (i < n) d[i] = f2bf(s[i]);
}

__global__ void k_zero(unsigned int* __restrict__ d, int n){
    int i = blockIdx.x * 256 + threadIdx.x;
    if (i < n) d[i] = 0u;
}

// transpose-cvt for Wp [256,256]: d[e*256+h] = s[h*256+e]
__global__ void k_cvt_t(const float* __restrict__ s, unsigned short* __restrict__ d){
    int e = blockIdx.x, h = threadIdx.x;
    d[e * 256 + h] = f2bf(s[h * 256 + e]);
}

// fused bias: bc[g<1024] = b0f[g] + Wi0f[g,:]@bp ; bc[g>=1024] = b0r[g-1024] + Wi0r[g-1024,:]@bp
__global__ void k_bias(const float* __restrict__ b0f, const float* __restrict__ Wi0f,
                       const float* __restrict__ b0r, const float* __restrict__ Wi0r,
                       const float* __restrict__ bp, float* __restrict__ bc){
    int g = blockIdx.x * 256 + threadIdx.x;
    const float* b = (g < 1024) ? b0f : b0r;
    const float* W = ((g < 1024) ? Wi0f : Wi0r) + (size_t)(g & 1023) * 256;
    float a = b[g & 1023];
    for (int k = 0; k < 256; ++k) a += W[k] * bp[k];
    bc[g] = a;
}

// ---------------------------------------------------------------- GEMM (weight-prep only): C[M,N] = A@W^T + bias
__global__ __launch_bounds__(256)
void k_gemm(const unsigned short* __restrict__ A, const unsigned short* __restrict__ W,
            const float* __restrict__ bias, unsigned short* __restrict__ C, int N)
{
    const int K = 256;
    __shared__ unsigned short Alds[128 * 32];
    __shared__ unsigned short Blds[128 * 32];
    const int tid = threadIdx.x, lane = tid & 63, wv = tid >> 6;
    const long m0 = (long)blockIdx.x * 128, n0 = (long)blockIdx.y * 128;
    const unsigned short* srcA[2]; const unsigned short* srcB[2]; int ldsOfs[2];
    #pragma unroll
    for (int q = 0; q < 2; ++q){
        int c = wv * 128 + q * 64 + lane;
        int r = c >> 2, kb = c & 3;
        int kg = kb ^ ((r >> 1) & 3);
        srcA[q] = A + (m0 + r) * K + kg * 8;
        srcB[q] = W + (n0 + r) * K + kg * 8;
        ldsOfs[q] = c * 8;
    }
    f4 acc[4][4] = {};
    const int ar = lane & 15, kq = lane >> 4;
    const int wm = (wv >> 1) * 64, wn = (wv & 1) * 64;
    for (int kk = 0; kk < K / 32; ++kk){
        i4 ra[2], rb[2];
        #pragma unroll
        for (int q = 0; q < 2; ++q){ ra[q] = *(const i4*)(srcA[q] + kk * 32); rb[q] = *(const i4*)(srcB[q] + kk * 32); }
        __syncthreads();
        #pragma unroll
        for (int q = 0; q < 2; ++q){ *(i4*)&Alds[ldsOfs[q]] = ra[q]; *(i4*)&Blds[ldsOfs[q]] = rb[q]; }
        __syncthreads();
        bf8 af[4], bfr[4];
        #pragma unroll
        for (int mt = 0; mt < 4; ++mt){
            int row = wm + mt * 16 + ar; int ph = kq ^ ((row >> 1) & 3);
            af[mt] = ld16(&Alds[row * 32 + ph * 8]);
        }
        #pragma unroll
        for (int nt = 0; nt < 4; ++nt){
            int row = wn + nt * 16 + ar; int ph = kq ^ ((row >> 1) & 3);
            bfr[nt] = ld16(&Blds[row * 32 + ph * 8]);
        }
        #pragma unroll
        for (int mt = 0; mt < 4; ++mt)
            #pragma unroll
            for (int nt = 0; nt < 4; ++nt)
                acc[mt][nt] = __builtin_amdgcn_mfma_f32_16x16x32_bf16(af[mt], bfr[nt], acc[mt][nt], 0, 0, 0);
    }
    #pragma unroll
    for (int nt = 0; nt < 4; ++nt){
        long n = n0 + wn + nt * 16 + ar;
        float bv = bias[n];
        #pragma unroll
        for (int mt = 0; mt < 4; ++mt)
            #pragma unroll
            for (int r = 0; r < 4; ++r){
                long m = m0 + wm + mt * 16 + kq * 4 + r;
                C[m * N + n] = f2bf(acc[mt][nt][r] + bv);
            }
    }
}

// ---------------------------------------------------------------- persistent bidirectional LSTM layer
// Grid: 128 blocks = 16 groups (pt 8 x dir 2) x 8 jc; block 256 thr = 4 waves (2 path-halves x 2 hcol-halves).
// Block owns (64 paths x 32 hcols, dir). Weights (Wh slice + Wx slice) VGPR-resident as MFMA B-frags.
// SIMPLE gate map: MFMA nt == gate (i,f,g,o); B-row for lane = nt*256 + hcbase + ar.
// C-frag: row(path)=kq*4+r, col=ar. Lane ar holds ALL 4 gates of hcol=hcbase+ar in acc[mt][0..3][r].
// Sync: per-wave lane0 system-scope acquire spin + per-thread threadfence (no single-thread transitivity).
template<int LAYER>
__global__ __launch_bounds__(256, 1)
void k_persist(const unsigned short* __restrict__ Whw,  // [2][1024][256] bf16
               const unsigned short* __restrict__ Wxw,  // L0: wc0 [2][1024][256]; L1: wi1 [2][1024][512]
               const float* __restrict__ bias0,         // L0: bc0 ; L1: b1f
               const float* __restrict__ bias1,         // L0: bc0+1024 ; L1: b1r
               const unsigned short* __restrict__ xsrc, // L0: emb_bf [N][256]; L1: o0 [131072][512]
               const int* __restrict__ seq,             // L0 only: [512][256]
               const int* __restrict__ lengths,         // [512]
               unsigned short* __restrict__ o0,         // L0 out: [131072][512] ([path*256+t][dir*256+hcol])
               unsigned short* __restrict__ hbuf,       // L1 out: [2 dir][2 parity][512][256]
               unsigned int* __restrict__ flags)        // [16][256]
{
    constexpr int XK = LAYER ? 512 : 256;
    const int tid = threadIdx.x, lane = tid & 63, wv = tid >> 6;
    const int b = blockIdx.x;
    const int g = b & 15, jc = b >> 4;
    const int pt = g >> 1, dir = g & 1;
    const int ph = wv >> 1, gh = wv & 1;
    const int pbase = pt * 64 + ph * 32;
    const int hcbase = jc * 32 + gh * 16;
    const int ar = lane & 15, kq = lane >> 4;
    unsigned int* myflag = flags + g * 256;

    // ---- load weight B-fragments into VGPRs (once); nt == gate ----
    bf8 whf[4][8], wxf[4][XK / 32];
    #pragma unroll
    for (int nt = 0; nt < 4; ++nt){
        const int wrow = nt * 256 + hcbase + ar;
        const unsigned short* wh = Whw + (size_t)(dir * 1024 + wrow) * 256 + kq * 8;
        const unsigned short* wx = Wxw + (size_t)(dir * 1024 + wrow) * XK + kq * 8;
        #pragma unroll
        for (int k0 = 0; k0 < 8; ++k0) whf[nt][k0] = ld16(wh + k0 * 32);
        #pragma unroll
        for (int k0 = 0; k0 < XK / 32; ++k0) wxf[nt][k0] = ld16(wx + k0 * 32);
    }
    // ---- per-lane owned cells: hcol = hcbase+ar, paths pbase + mt*16 + kq*4 + r ----
    const int hcol = hcbase + ar;
    const float* bb = dir ? bias1 : bias0;
    const float bI = bb[hcol], bF = bb[256 + hcol], bG = bb[512 + hcol], bO = bb[768 + hcol];
    int len_[2][4];
    #pragma unroll
    for (int mt = 0; mt < 2; ++mt)
        #pragma unroll
        for (int r = 0; r < 4; ++r) len_[mt][r] = lengths[pbase + mt * 16 + kq * 4 + r];
    float cst[2][4] = {}, hst[2][4] = {};

    for (int s = 0; s < 256; ++s){
        const int t = dir ? 255 - s : s;
        f4 acc[2][4] = {};
        // ---- x-phase (static inputs only; overlaps the group-barrier latency) ----
        {
            const unsigned short* xb[2];
            #pragma unroll
            for (int mt = 0; mt < 2; ++mt){
                const int pa = pbase + mt * 16 + ar;
                if constexpr (LAYER == 0){
                    int e = seq[pa * 256 + t];
                    xb[mt] = xsrc + (size_t)e * 256 + kq * 8;
                } else {
                    xb[mt] = xsrc + ((size_t)pa * 256 + t) * 512 + kq * 8;
                }
            }
            #pragma unroll
            for (int k0 = 0; k0 < XK / 32; ++k0){
                bf8 a0 = ld16(xb[0] + k0 * 32);
                bf8 a1 = ld16(xb[1] + k0 * 32);
                #pragma unroll
                for (int nt = 0; nt < 4; ++nt){
                    acc[0][nt] = __builtin_amdgcn_mfma_f32_16x16x32_bf16(a0, wxf[nt][k0], acc[0][nt], 0, 0, 0);
                    acc[1][nt] = __builtin_amdgcn_mfma_f32_16x16x32_bf16(a1, wxf[nt][k0], acc[1][nt], 0, 0, 0);
                }
            }
        }
        // ---- wait for group step s-1 (every wave acquires), then h-phase ----
        if (s > 0){
            if (lane == 0){
                unsigned int guard = 0;
                while (__hip_atomic_load(myflag + (s - 1), __ATOMIC_ACQUIRE, __HIP_MEMORY_SCOPE_SYSTEM) < 8u){
                    if (++guard > 2000000u) break;   // protocol failure -> wrong answer, never a wedge
                    __builtin_amdgcn_s_sleep(1);
                }
            }
            __syncthreads();
            __threadfence();   // per-thread device-scope acquire fence before h loads
            const int tprev = dir ? t + 1 : t - 1;
            const unsigned short* hb[2];
            #pragma unroll
            for (int mt = 0; mt < 2; ++mt){
                const int pa = pbase + mt * 16 + ar;
                if constexpr (LAYER == 0)
                    hb[mt] = o0 + ((size_t)pa * 256 + tprev) * 512 + dir * 256 + kq * 8;
                else
                    hb[mt] = hbuf + ((size_t)((dir * 2 + ((s - 1) & 1)) * 512) + pa) * 256 + kq * 8;
            }
            #pragma unroll
            for (int k0 = 0; k0 < 8; ++k0){
                bf8 a0 = ld16(hb[0] + k0 * 32);
                bf8 a1 = ld16(hb[1] + k0 * 32);
                #pragma unroll
                for (int nt = 0; nt < 4; ++nt){
                    acc[0][nt] = __builtin_amdgcn_mfma_f32_16x16x32_bf16(a0, whf[nt][k0], acc[0][nt], 0, 0, 0);
                    acc[1][nt] = __builtin_amdgcn_mfma_f32_16x16x32_bf16(a1, whf[nt][k0], acc[1][nt], 0, 0, 0);
                }
            }
        }
        // ---- epilogue: all 4 gates are lane-local ----
        #pragma unroll
        for (int mt = 0; mt < 2; ++mt){
            #pragma unroll
            for (int r = 0; r < 4; ++r){
                float zi = acc[mt][0][r] + bI;
                float zf = acc[mt][1][r] + bF;
                float zg = acc[mt][2][r] + bG;
                float zo = acc[mt][3][r] + bO;
                const int pa = pbase + mt * 16 + kq * 4 + r;
                const bool m = t < len_[mt][r];
                float cn = sigm(zf) * cst[mt][r] + sigm(zi) * tanh_fast(zg);
                float hn = sigm(zo) * tanh_fast(cn);
                if (m){ cst[mt][r] = cn; hst[mt][r] = hn; }
                const unsigned short hb16 = f2bf(hst[mt][r]);
                if constexpr (LAYER == 0)
                    o0[((size_t)pa * 256 + t) * 512 + dir * 256 + hcol] = hb16;
                else
                    hbuf[((size_t)((dir * 2 + (s & 1)) * 512) + pa) * 256 + hcol] = hb16;
            }
        }
        // ---- publish step s ----
        __threadfence();
        __syncthreads();
        if (tid == 0)
            __hip_atomic_fetch_add(myflag + s, 1u, __ATOMIC_RELEASE, __HIP_MEMORY_SCOPE_SYSTEM);
    }
}

// ---------------------------------------------------------------- head: path_feat + fuse + score
__global__ __launch_bounds__(256)
void k_fuse(const unsigned short* __restrict__ hbuf,  // [2][2][512][256], read parity 1
            const float* __restrict__ features, const float* __restrict__ Wf, const float* __restrict__ bfv,
            const float* __restrict__ Wfus, const float* __restrict__ bfus,
            const float* __restrict__ Wa, const float* __restrict__ ba,
            float* __restrict__ pe, float* __restrict__ scores)
{
    __shared__ float comb[768];
    __shared__ float fl[64];
    __shared__ float red[256];
    const int p = blockIdx.x, tid = threadIdx.x;
    comb[tid]       = bf2f(hbuf[((size_t)(0 * 2 + 1) * 512 + p) * 256 + tid]);
    comb[256 + tid] = bf2f(hbuf[((size_t)(1 * 2 + 1) * 512 + p) * 256 + tid]);
    if (tid < 64) fl[tid] = features[p * 64 + tid];
    __syncthreads();
    float pf = bfv[tid];
    #pragma unroll 4
    for (int k = 0; k < 64; ++k) pf += fl[k] * Wf[tid * 64 + k];
    comb[512 + tid] = pf;
    __syncthreads();
    float a = bfus[tid];
    #pragma unroll 4
    for (int k = 0; k < 768; ++k) a += comb[k] * Wfus[tid * 768 + k];
    float pev = fmaxf(a, 0.f);
    pe[(size_t)p * 256 + tid] = pev;
    red[tid] = pev * Wa[tid];
    __syncthreads();
    for (int ofs = 128; ofs > 0; ofs >>= 1){
        if (tid < ofs) red[tid] += red[tid + ofs];
        __syncthreads();
    }
    if (tid == 0) scores[p] = red[0] + ba[0];
}

// ---------------------------------------------------------------- head: softmax + aggregate + MLP
__global__ __launch_bounds__(512)
void k_head(const float* __restrict__ pe, const float* __restrict__ scores,
            const float* __restrict__ W1, const float* __restrict__ b1,
            const float* __restrict__ W2, const float* __restrict__ b2,
            float* __restrict__ out)
{
    __shared__ float att[512];
    __shared__ float red[512];
    __shared__ float agg[768];
    __shared__ float h1[512];
    const int tid = threadIdx.x;
    float s = scores[tid];
    red[tid] = s; __syncthreads();
    for (int ofs = 256; ofs > 0; ofs >>= 1){ if (tid < ofs) red[tid] = fmaxf(red[tid], red[tid + ofs]); __syncthreads(); }
    float mx = red[0]; __syncthreads();
    float e = __expf(s - mx);
    red[tid] = e; __syncthreads();
    for (int ofs = 256; ofs > 0; ofs >>= 1){ if (tid < ofs) red[tid] += red[tid + ofs]; __syncthreads(); }
    float sum = red[0]; __syncthreads();
    att[tid] = e / sum;
    __syncthreads();
    if (tid < 256){
        float w = 0.f, sm = 0.f, mxv = -1e30f;
        for (int p = 0; p < 512; ++p){
            float v = pe[(size_t)p * 256 + tid];
            w += att[p] * v; sm += v; mxv = fmaxf(mxv, v);
        }
        agg[tid] = w; agg[256 + tid] = sm * (1.f / 512.f); agg[512 + tid] = mxv;
    }
    __syncthreads();
    float hv = b1[tid];
    #pragma unroll 4
    for (int k = 0; k < 768; ++k) hv += agg[k] * W1[tid * 768 + k];
    hv = fmaxf(hv, 0.f);
    h1[tid] = hv;
    __syncthreads();
    if (tid < 256){
        float o = b2[tid];
        #pragma unroll 4
        for (int k = 0; k < 512; ++k) o += h1[k] * W2[tid * 512 + k];
        out[tid] = o;
    }
}

// ----------------------------------------------------------------
extern "C" void kernel_launch(void* const* d_in, const int* in_sizes, int n_in,
                              void* d_out, int out_size, void* d_ws, size_t ws_size,
                              hipStream_t stream)
{
    const int*   seq  = (const int*)  d_in[0];
    const int*   len  = (const int*)  d_in[1];
    const float* feat = (const float*)d_in[2];
    const float* emb  = (const float*)d_in[3];
    const float* Wp   = (const float*)d_in[5];
    const float* bp   = (const float*)d_in[6];
    const float* Wi0f = (const float*)d_in[7];
    const float* Wh0f = (const float*)d_in[8];
    const float* b0f  = (const float*)d_in[9];
    const float* Wi0r = (const float*)d_in[10];
    const float* Wh0r = (const float*)d_in[11];
    const float* b0r  = (const float*)d_in[12];
    const float* Wi1f = (const float*)d_in[13];
    const float* Wh1f = (const float*)d_in[14];
    const float* b1f  = (const float*)d_in[15];
    const float* Wi1r = (const float*)d_in[16];
    const float* Wh1r = (const float*)d_in[17];
    const float* b1r  = (const float*)d_in[18];
    const float* Wf   = (const float*)d_in[19];
    const float* bfv  = (const float*)d_in[20];
    const float* Wfus = (const float*)d_in[21];
    const float* bfus = (const float*)d_in[22];
    const float* Wa   = (const float*)d_in[23];
    const float* ba   = (const float*)d_in[24];
    const float* W1   = (const float*)d_in[25];
    const float* b1   = (const float*)d_in[26];
    const float* W2   = (const float*)d_in[27];
    const float* b2   = (const float*)d_in[28];

    char* ws = (char*)d_ws;
    size_t o = 0;
    auto alloc = [&](size_t bytes)->char*{ char* r = ws + o; o += (bytes + 255) & ~(size_t)255; return r; };

    unsigned short* emb_bf = (unsigned short*)alloc(50000UL * 256 * 2);    // 25.6 MB
    unsigned short* wpT    = (unsigned short*)alloc(256UL * 256 * 2);
    unsigned short* wi0b   = (unsigned short*)alloc(2048UL * 256 * 2);
    unsigned short* wc0    = (unsigned short*)alloc(2048UL * 256 * 2);     // Wi0·Wp fused, bf16
    float*          bc0    = (float*)        alloc(2048UL * 4);            // b0 + Wi0·bp
    float*          zbias  = (float*)        alloc(256UL * 4);
    unsigned short* wi1b   = (unsigned short*)alloc(2048UL * 512 * 2);
    unsigned short* wh0b   = (unsigned short*)alloc(2048UL * 256 * 2);
    unsigned short* wh1b   = (unsigned short*)alloc(2048UL * 256 * 2);
    unsigned short* o0p    = (unsigned short*)alloc(131072UL * 512 * 2);   // 128 MB
    unsigned short* hbuf   = (unsigned short*)alloc(4UL * 512 * 256 * 2);  // [dir][parity][512][256]
    unsigned int*   flags0 = (unsigned int*) alloc(16UL * 256 * 4);
    unsigned int*   flags1 = (unsigned int*) alloc(16UL * 256 * 4);
    float*          pe     = (float*)        alloc(512UL * 256 * 4);
    float*          scores = (float*)        alloc(512UL * 4);
    (void)in_sizes; (void)n_in; (void)out_size;
    if (o > ws_size) return;   // fail cleanly rather than stomping memory

    auto cvt = [&](const float* s, unsigned short* d, int n){
        k_cvt<<<(n + 255) / 256, 256, 0, stream>>>(s, d, n);
    };
    cvt(emb,  emb_bf, 50000 * 256);
    k_cvt_t<<<256, 256, 0, stream>>>(Wp, wpT);
    cvt(Wi0f, wi0b,              1024 * 256);
    cvt(Wi0r, wi0b + 1024 * 256, 1024 * 256);
    cvt(Wh0f, wh0b,              1024 * 256);
    cvt(Wh0r, wh0b + 1024 * 256, 1024 * 256);
    cvt(Wi1f, wi1b,              1024 * 512);
    cvt(Wi1r, wi1b + 1024 * 512, 1024 * 512);
    cvt(Wh1f, wh1b,              1024 * 256);
    cvt(Wh1r, wh1b + 1024 * 256, 1024 * 256);
    k_bias<<<8, 256, 0, stream>>>(b0f, Wi0f, b0r, Wi0r, bp, bc0);
    // zero ONLY the flag arrays (contiguous 2*16384B) and zbias (1024B) — nothing else.
    k_zero<<<32, 256, 0, stream>>>(flags0, 16 * 256 * 2);
    k_zero<<<1, 256, 0, stream>>>((unsigned int*)zbias, 256);

    // Wc0[2048,256] = wi0b @ wpT^T  (fused projection weight)
    k_gemm<<<dim3(16, 2), 256, 0, stream>>>(wi0b, wpT, zbias, wc0, 256);

    // layer 0 (persistent, 256 steps in-kernel)
    k_persist<0><<<128, 256, 0, stream>>>(wh0b, wc0, bc0, bc0 + 1024, emb_bf, seq, len,
                                          o0p, nullptr, flags0);
    // layer 1
    k_persist<1><<<128, 256, 0, stream>>>(wh1b, wi1b, b1f, b1r, o0p, nullptr, len,
                                          nullptr, hbuf, flags1);
    // head
    k_fuse<<<512, 256, 0, stream>>>(hbuf, feat, Wf, bfv, Wfus, bfus, Wa, ba, pe, scores);
    k_head<<<1, 512, 0, stream>>>(pe, scores, W1, b1, W2, b2, (float*)d_out);
}